// Round 1
// baseline (615.350 us; speedup 1.0000x reference)
//
#include <hip/hip_runtime.h>
#include <math.h>

// Problem constants: x[8,64,256,256] f32, weight[64,16,3,3] f32, bias[64] f32
// out[8, 64+48, 256, 256] f32
#define HW_ 65536
#define C_ 64
#define B_ 8
#define P_ 16
#define OC_ 64
#define OUTC_ 112

// ---------------------------------------------------------------------------
// Kernel 1: per-(b,c) min/max + 256-bin histogram + entropy.
// One block per (b,c). Binning must replicate reference fp32 math exactly:
//   q = (x - min) / (max - min + 1e-8f)   [IEEE div]
//   bin = (int)(q * 256.0f)  clamped to [0,255]   [*256 is exact]
// ---------------------------------------------------------------------------
__global__ __launch_bounds__(256) void stats_kernel(const float* __restrict__ x,
                                                    float* __restrict__ act) {
    const int bc = blockIdx.x;  // 0..511
    const int tid = threadIdx.x;
    const float4* xv = (const float4*)(x + (size_t)bc * HW_);

    __shared__ float smn[256];
    __shared__ float smx[256];
    __shared__ unsigned int hist[256];
    __shared__ float sred[256];
    __shared__ float s_mn, s_den;

    hist[tid] = 0u;

    float mn = 3.402823466e38f, mx = -3.402823466e38f;
    #pragma unroll 8
    for (int k = 0; k < 64; ++k) {
        float4 v = xv[tid + k * 256];
        mn = fminf(mn, fminf(fminf(v.x, v.y), fminf(v.z, v.w)));
        mx = fmaxf(mx, fmaxf(fmaxf(v.x, v.y), fmaxf(v.z, v.w)));
    }
    smn[tid] = mn; smx[tid] = mx;
    __syncthreads();
    for (int s = 128; s > 0; s >>= 1) {
        if (tid < s) {
            smn[tid] = fminf(smn[tid], smn[tid + s]);
            smx[tid] = fmaxf(smx[tid], smx[tid + s]);
        }
        __syncthreads();
    }
    if (tid == 0) {
        s_mn = smn[0];
        s_den = (smx[0] - smn[0]) + 1e-8f;  // exact reference expression
    }
    __syncthreads();
    const float lmn = s_mn;
    const float lden = s_den;

    #pragma unroll 4
    for (int k = 0; k < 64; ++k) {
        float4 v = xv[tid + k * 256];
        float q0 = (v.x - lmn) / lden;
        float q1 = (v.y - lmn) / lden;
        float q2 = (v.z - lmn) / lden;
        float q3 = (v.w - lmn) / lden;
        int b0 = (int)(q0 * 256.0f); b0 = min(max(b0, 0), 255);
        int b1 = (int)(q1 * 256.0f); b1 = min(max(b1, 0), 255);
        int b2 = (int)(q2 * 256.0f); b2 = min(max(b2, 0), 255);
        int b3 = (int)(q3 * 256.0f); b3 = min(max(b3, 0), 255);
        atomicAdd(&hist[b0], 1u);
        atomicAdd(&hist[b1], 1u);
        atomicAdd(&hist[b2], 1u);
        atomicAdd(&hist[b3], 1u);
    }
    __syncthreads();

    // entropy: hist sum is exactly 65536.0f in fp32 (eps terms vanish),
    // so prob = (count + 1e-8f) * 2^-16 exactly matches hist/hist.sum().
    float h = (float)hist[tid] + 1e-8f;
    float p = h * (1.0f / 65536.0f);
    float term = p * logf(p + 1e-8f);
    sred[tid] = term;
    __syncthreads();
    for (int s = 128; s > 0; s >>= 1) {
        if (tid < s) sred[tid] += sred[tid + s];
        __syncthreads();
    }
    if (tid == 0) act[bc] = -sred[0];
}

// ---------------------------------------------------------------------------
// Kernel 2: per-batch top-16 (descending, tie -> lower index, matching
// jax.lax.top_k) + ascending unselected list. One block (64 threads) / batch.
// ---------------------------------------------------------------------------
__global__ __launch_bounds__(64) void select_kernel(const float* __restrict__ act,
                                                    int* __restrict__ sel,
                                                    int* __restrict__ unsel) {
    const int b = blockIdx.x;
    const int lane = threadIdx.x;  // 0..63, one per channel
    float v = act[b * 64 + lane];
    bool alive = true;

    for (int p = 0; p < 16; ++p) {
        float bv = alive ? v : -3.402823466e38f;
        int bi = lane;
        #pragma unroll
        for (int off = 32; off > 0; off >>= 1) {
            float ov = __shfl_xor(bv, off);
            int oi = __shfl_xor(bi, off);
            if (ov > bv || (ov == bv && oi < bi)) { bv = ov; bi = oi; }
        }
        if (lane == 0) sel[b * 16 + p] = bi;
        if (lane == bi) alive = false;
    }
    unsigned long long mask = __ballot(alive);
    if (alive) {
        int r = __popcll(mask & ((1ull << lane) - 1ull));
        unsel[b * 48 + r] = lane;  // ascending channel order by construction
    }
}

// ---------------------------------------------------------------------------
// Kernel 3: copy the 48 unselected channels (ascending) to out channels 64..111
// ---------------------------------------------------------------------------
__global__ __launch_bounds__(256) void copy_kernel(const float4* __restrict__ x,
                                                   const int* __restrict__ unsel,
                                                   float4* __restrict__ out) {
    const int bid = blockIdx.x;
    const int j = bid >> 6;        // 0..383  (b, r)
    const int blk = bid & 63;
    const int b = j / 48;
    const int r = j - b * 48;
    const int c = unsel[b * 48 + r];
    const int i = blk * 256 + threadIdx.x;  // float4 index within channel
    out[((size_t)(b * OUTC_ + 64 + r)) * 16384 + i] =
        x[((size_t)(b * C_ + c)) * 16384 + i];
}

// ---------------------------------------------------------------------------
// Kernel 4: 3x3 conv, 16 gathered input channels -> 64 oc, padding 1.
// Block: 32x32 output tile, one batch, 32 of 64 oc. 256 threads, 2x2 px each.
// Input channels staged in LDS 8 at a time (gathered from x via sel).
// ---------------------------------------------------------------------------
__global__ __launch_bounds__(256) void conv_kernel(const float* __restrict__ x,
                                                   const float* __restrict__ w,
                                                   const float* __restrict__ bias,
                                                   const int* __restrict__ sel,
                                                   float* __restrict__ out) {
    __shared__ float in_t[8][34][34];   // 37 KB
    __shared__ float w_t[8 * 9 * 32];   // 9 KB   [p][tap][ocl]
    __shared__ int sch[16];

    const int tid = threadIdx.x;
    const int bid = blockIdx.x;
    const int b = bid >> 7;
    const int rem = bid & 127;
    const int half = rem & 1;
    const int tile = rem >> 1;       // 0..63
    const int ty = tile >> 3, tx = tile & 7;
    const int oc0 = half << 5;

    if (tid < 16) sch[tid] = sel[b * 16 + tid];

    const int px = (tid & 15) << 1;  // 0,2,..,30
    const int py = (tid >> 4) << 1;  // 0,2,..,30
    const int gy0 = ty * 32 - 1, gx0 = tx * 32 - 1;

    float acc[4][32];
    #pragma unroll
    for (int pix = 0; pix < 4; ++pix)
        #pragma unroll
        for (int o = 0; o < 32; ++o) acc[pix][o] = 0.0f;

    for (int pg = 0; pg < 2; ++pg) {
        __syncthreads();
        // stage 8 gathered input channels (34x34 halo tile each)
        for (int i = tid; i < 8 * 34 * 34; i += 256) {
            int ch = i / 1156;
            int r2 = i - ch * 1156;
            int iy = r2 / 34;
            int ix = r2 - iy * 34;
            int gy = gy0 + iy, gx = gx0 + ix;
            float v = 0.0f;
            if ((unsigned)gy < 256u && (unsigned)gx < 256u)
                v = x[(((size_t)b * C_ + sch[pg * 8 + ch]) * 256 + gy) * 256 + gx];
            in_t[ch][iy][ix] = v;
        }
        // stage weights for this (oc half, channel group): [p][tap][ocl]
        for (int i = tid; i < 2304; i += 256) {
            int ocl = i & 31;
            int t2 = i >> 5;             // p*9+tap
            int p = t2 / 9, tap = t2 - p * 9;
            w_t[t2 * 32 + ocl] = w[((size_t)(oc0 + ocl) * 16 + (pg * 8 + p)) * 9 + tap];
        }
        __syncthreads();

        #pragma unroll
        for (int p = 0; p < 8; ++p) {
            float patch[4][4];
            #pragma unroll
            for (int r = 0; r < 4; ++r)
                #pragma unroll
                for (int c = 0; c < 4; ++c)
                    patch[r][c] = in_t[p][py + r][px + c];
            #pragma unroll
            for (int tap = 0; tap < 9; ++tap) {
                const int dy = tap / 3, dx = tap - (tap / 3) * 3;
                #pragma unroll
                for (int o = 0; o < 32; ++o) {
                    float wv = w_t[(p * 9 + tap) * 32 + o];
                    acc[0][o] += patch[dy][dx] * wv;
                    acc[1][o] += patch[dy][dx + 1] * wv;
                    acc[2][o] += patch[dy + 1][dx] * wv;
                    acc[3][o] += patch[dy + 1][dx + 1] * wv;
                }
            }
        }
    }

    // epilogue: bias + coalesced float2 stores
    const int gy = ty * 32 + py, gx = tx * 32 + px;
    #pragma unroll
    for (int o = 0; o < 32; ++o) {
        float bv = bias[oc0 + o];
        size_t base = ((size_t)b * OUTC_ + (oc0 + o)) * HW_;
        float2 r0; r0.x = acc[0][o] + bv; r0.y = acc[1][o] + bv;
        float2 r1; r1.x = acc[2][o] + bv; r1.y = acc[3][o] + bv;
        *(float2*)&out[base + (size_t)gy * 256 + gx] = r0;
        *(float2*)&out[base + (size_t)(gy + 1) * 256 + gx] = r1;
    }
}

extern "C" void kernel_launch(void* const* d_in, const int* in_sizes, int n_in,
                              void* d_out, int out_size, void* d_ws, size_t ws_size,
                              hipStream_t stream) {
    const float* x = (const float*)d_in[0];     // [8,64,256,256]
    const float* w = (const float*)d_in[1];     // [64,16,3,3]
    const float* bias = (const float*)d_in[2];  // [64]
    float* out = (float*)d_out;                 // [8,112,256,256]

    float* act = (float*)d_ws;                  // 512 floats
    int* sel = (int*)d_ws + 512;                // 8*16
    int* unsel = sel + 128;                     // 8*48

    stats_kernel<<<512, 256, 0, stream>>>(x, act);
    select_kernel<<<8, 64, 0, stream>>>(act, sel, unsel);
    copy_kernel<<<24576, 256, 0, stream>>>((const float4*)x, unsel, (float4*)out);
    conv_kernel<<<1024, 256, 0, stream>>>(x, w, bias, sel, out);
}

// Round 2
// 417.861 us; speedup vs baseline: 1.4726x; 1.4726x over previous
//
#include <hip/hip_runtime.h>
#include <hip/hip_bf16.h>
#include <math.h>

#define HW_ 65536
#define C_ 64
#define B_ 8
#define OUTC_ 112

typedef short bf16x8 __attribute__((ext_vector_type(8)));
typedef float f32x4 __attribute__((ext_vector_type(4)));

// ---------------------------------------------------------------------------
// Kernel 1: per-(b,c) min/max + 256-bin histogram + entropy.
// 16 replicated LDS histograms (stride 257) to break atomic serialization on
// Gaussian-centered bins. Binning replicates reference fp32 math exactly.
// ---------------------------------------------------------------------------
__global__ __launch_bounds__(256) void stats_kernel(const float* __restrict__ x,
                                                    float* __restrict__ act) {
    const int bc = blockIdx.x;  // 0..511
    const int tid = threadIdx.x;
    const float4* xv = (const float4*)(x + (size_t)bc * HW_);

    __shared__ unsigned int hist[16 * 257];
    __shared__ float smn[256];
    __shared__ float smx[256];
    __shared__ float sred[256];
    __shared__ float s_mn, s_den;

    for (int i = tid; i < 16 * 257; i += 256) hist[i] = 0u;

    float mn = 3.402823466e38f, mx = -3.402823466e38f;
    #pragma unroll 8
    for (int k = 0; k < 64; ++k) {
        float4 v = xv[tid + k * 256];
        mn = fminf(mn, fminf(fminf(v.x, v.y), fminf(v.z, v.w)));
        mx = fmaxf(mx, fmaxf(fmaxf(v.x, v.y), fmaxf(v.z, v.w)));
    }
    smn[tid] = mn; smx[tid] = mx;
    __syncthreads();
    for (int s = 128; s > 0; s >>= 1) {
        if (tid < s) {
            smn[tid] = fminf(smn[tid], smn[tid + s]);
            smx[tid] = fmaxf(smx[tid], smx[tid + s]);
        }
        __syncthreads();
    }
    if (tid == 0) {
        s_mn = smn[0];
        s_den = (smx[0] - smn[0]) + 1e-8f;  // exact reference expression
    }
    __syncthreads();
    const float lmn = s_mn;
    const float lden = s_den;
    const int rep = (tid & 15) * 257;

    #pragma unroll 4
    for (int k = 0; k < 64; ++k) {
        float4 v = xv[tid + k * 256];
        float q0 = (v.x - lmn) / lden;
        float q1 = (v.y - lmn) / lden;
        float q2 = (v.z - lmn) / lden;
        float q3 = (v.w - lmn) / lden;
        int b0 = (int)(q0 * 256.0f); b0 = min(max(b0, 0), 255);
        int b1 = (int)(q1 * 256.0f); b1 = min(max(b1, 0), 255);
        int b2 = (int)(q2 * 256.0f); b2 = min(max(b2, 0), 255);
        int b3 = (int)(q3 * 256.0f); b3 = min(max(b3, 0), 255);
        atomicAdd(&hist[rep + b0], 1u);
        atomicAdd(&hist[rep + b1], 1u);
        atomicAdd(&hist[rep + b2], 1u);
        atomicAdd(&hist[rep + b3], 1u);
    }
    __syncthreads();

    // merge replicas for bin=tid, then entropy
    unsigned int cnt = 0;
    #pragma unroll
    for (int r = 0; r < 16; ++r) cnt += hist[r * 257 + tid];
    float h = (float)cnt + 1e-8f;
    float p = h * (1.0f / 65536.0f);   // sum is exactly 65536.0f in fp32
    sred[tid] = p * logf(p + 1e-8f);
    __syncthreads();
    for (int s = 128; s > 0; s >>= 1) {
        if (tid < s) sred[tid] += sred[tid + s];
        __syncthreads();
    }
    if (tid == 0) act[bc] = -sred[0];
}

// ---------------------------------------------------------------------------
// Kernel 2: per-batch top-16 (desc, tie->lower idx) + ascending unselected.
// ---------------------------------------------------------------------------
__global__ __launch_bounds__(64) void select_kernel(const float* __restrict__ act,
                                                    int* __restrict__ sel,
                                                    int* __restrict__ unsel) {
    const int b = blockIdx.x;
    const int lane = threadIdx.x;
    float v = act[b * 64 + lane];
    bool alive = true;

    for (int p = 0; p < 16; ++p) {
        float bv = alive ? v : -3.402823466e38f;
        int bi = lane;
        #pragma unroll
        for (int off = 32; off > 0; off >>= 1) {
            float ov = __shfl_xor(bv, off);
            int oi = __shfl_xor(bi, off);
            if (ov > bv || (ov == bv && oi < bi)) { bv = ov; bi = oi; }
        }
        if (lane == 0) sel[b * 16 + p] = bi;
        if (lane == bi) alive = false;
    }
    unsigned long long mask = __ballot(alive);
    if (alive) {
        int r = __popcll(mask & ((1ull << lane) - 1ull));
        unsel[b * 48 + r] = lane;
    }
}

// ---------------------------------------------------------------------------
// Kernel 3: copy 48 unselected channels to out channels 64..111
// ---------------------------------------------------------------------------
__global__ __launch_bounds__(256) void copy_kernel(const float4* __restrict__ x,
                                                   const int* __restrict__ unsel,
                                                   float4* __restrict__ out) {
    const int bid = blockIdx.x;
    const int j = bid >> 6;
    const int blk = bid & 63;
    const int b = j / 48;
    const int r = j - b * 48;
    const int c = unsel[b * 48 + r];
    const int i = blk * 256 + threadIdx.x;
    out[((size_t)(b * OUTC_ + 64 + r)) * 16384 + i] =
        x[((size_t)(b * C_ + c)) * 16384 + i];
}

// ---------------------------------------------------------------------------
// Kernel 4: bf16-MFMA 3x3 conv, 16 gathered channels -> 64 oc.
// Block: 128-px row segment, 8 output rows, all 64 oc. 4 waves, each owns
// 32 px x 64 oc. K = 16ch x 9tap = 144, padded to 160 = 5 tap-pairs of K=32.
// Input rows staged in rolling LDS buffer [slot][ix][p] (p contiguous ->
// B-frag = one ds_read_b128). Weights held in registers (20 A-frags).
// ---------------------------------------------------------------------------
__global__ __launch_bounds__(256, 2) void conv_mfma_kernel(
    const float* __restrict__ x, const float* __restrict__ w,
    const float* __restrict__ bias, const int* __restrict__ sel,
    float* __restrict__ out) {
    __shared__ unsigned short Xt[5][132][16];    // [slot][ix][p]; slot4 = zeros
    __shared__ unsigned short A_lds[5][64][32];  // [kc][oc][kl]
    __shared__ int sch[16];

    const int tid = threadIdx.x;
    const int bid = blockIdx.x;
    const int b = bid >> 6;          // 512 blocks: 8 b x 2 xh x 32 ychunks
    const int rem = bid & 63;
    const int xh = rem & 1;
    const int y0 = (rem >> 1) * 8;
    const int x0 = xh * 128;

    if (tid < 16) sch[tid] = sel[b * 16 + tid];

    // zero pad slot (read for the padded tap 9)
    for (int i = tid; i < 132 * 16; i += 256) ((unsigned short*)Xt[4])[i] = 0;

    // weights -> A_lds[kc][oc][kl]: kl = t_in_pair*16 + p, tap = 2*kc + (kl>>4)
    for (int i = tid; i < 5 * 64 * 32; i += 256) {
        int kc = i >> 11;
        int r2 = i & 2047;
        int oc = r2 >> 5;
        int kl = r2 & 31;
        int p = kl & 15;
        int tap = kc * 2 + (kl >> 4);
        float v = (tap < 9) ? w[(oc * 16 + p) * 9 + tap] : 0.0f;
        __hip_bfloat16 hb = __float2bfloat16(v);
        A_lds[kc][oc][kl] = *(unsigned short*)&hb;
    }
    __syncthreads();

    const int lane = tid & 63;
    const int wv = tid >> 6;         // wave 0..3 -> px base wv*32
    const int n = lane & 15;         // m (oc) for A, n (px) for B, col for D
    const int g = lane >> 4;         // quad
    const int p0 = (g & 1) * 8;
    const int th = g >> 1;           // 0 -> first tap of pair, 1 -> second
    const int pxb = wv * 32;

    // preload all 20 A fragments into registers
    bf16x8 afr[5][4];
    #pragma unroll
    for (int kc = 0; kc < 5; ++kc)
        #pragma unroll
        for (int ocg = 0; ocg < 4; ++ocg)
            afr[kc][ocg] = *(const bf16x8*)&A_lds[kc][ocg * 16 + n][g * 8];

    // bias per (ocg, reg): oc = ocg*16 + g*4 + r
    float bv[4][4];
    #pragma unroll
    for (int ocg = 0; ocg < 4; ++ocg)
        #pragma unroll
        for (int r = 0; r < 4; ++r)
            bv[ocg][r] = bias[ocg * 16 + g * 4 + r];

    // row staging: thread (ch = tid>>4, l16 = tid&15) covers ix = m2*16+l16
    const int sch_ch = tid >> 4;
    const int l16 = tid & 15;
    const int mych = sch[sch_ch];
    const float* srcbase = x + ((size_t)(b * C_ + mych) << 16);

    float r0[9], r1[9], r2[9];
    #define LOAD_ROW(row, vr)                                            \
        {                                                                 \
            const float* src = srcbase + (row) * 256;                     \
            _Pragma("unroll")                                             \
            for (int m2 = 0; m2 < 9; ++m2) {                              \
                int ix = m2 * 16 + l16;                                   \
                int gx = x0 - 1 + ix;                                     \
                float v = 0.0f;                                           \
                if ((row) >= 0 && (row) < 256 && ix < 130 &&              \
                    gx >= 0 && gx < 256)                                  \
                    v = src[gx];                                          \
                (vr)[m2] = v;                                             \
            }                                                             \
        }
    #define STORE_ROW(slot, vr)                                          \
        {                                                                 \
            _Pragma("unroll")                                             \
            for (int m2 = 0; m2 < 9; ++m2) {                              \
                int ix = m2 * 16 + l16;                                   \
                if (ix < 130) {                                           \
                    __hip_bfloat16 hb = __float2bfloat16((vr)[m2]);       \
                    Xt[slot][ix][sch_ch] = *(unsigned short*)&hb;         \
                }                                                         \
            }                                                             \
        }

    LOAD_ROW(y0 - 1, r0)
    LOAD_ROW(y0, r1)
    LOAD_ROW(y0 + 1, r2)
    STORE_ROW((y0 - 1) & 3, r0)
    STORE_ROW(y0 & 3, r1)
    STORE_ROW((y0 + 1) & 3, r2)
    __syncthreads();

    for (int y = y0; y < y0 + 8; ++y) {
        // prefetch row y+2 into registers (overlaps with MFMA below)
        float pv[9];
        const bool doPref = (y + 2 <= y0 + 8);
        if (doPref) LOAD_ROW(y + 2, pv)

        f32x4 acc[2][4];
        #pragma unroll
        for (int ng = 0; ng < 2; ++ng)
            #pragma unroll
            for (int ocg = 0; ocg < 4; ++ocg)
                acc[ng][ocg] = (f32x4){0.f, 0.f, 0.f, 0.f};

        #pragma unroll
        for (int kc = 0; kc < 5; ++kc) {
            const int t0 = 2 * kc, t1 = 2 * kc + 1;
            const int dy0 = t0 / 3, dx0 = t0 % 3;
            const int dy1 = (t1 <= 8) ? t1 / 3 : 0;
            const int dx1 = (t1 <= 8) ? t1 % 3 : 0;
            const int slot0 = (y - 1 + dy0) & 3;
            const int slot1 = (t1 <= 8) ? ((y - 1 + dy1) & 3) : 4;
            const int slotT = th ? slot1 : slot0;
            const int dxT = th ? dx1 : dx0;
            #pragma unroll
            for (int ng = 0; ng < 2; ++ng) {
                const int ix = pxb + ng * 16 + n + dxT;
                const bf16x8 bb = *(const bf16x8*)&Xt[slotT][ix][p0];
                #pragma unroll
                for (int ocg = 0; ocg < 4; ++ocg)
                    acc[ng][ocg] = __builtin_amdgcn_mfma_f32_16x16x32_bf16(
                        afr[kc][ocg], bb, acc[ng][ocg], 0, 0, 0);
            }
        }

        // epilogue: D col = px = lane&15, row(oc_local) = g*4 + r
        #pragma unroll
        for (int ng = 0; ng < 2; ++ng)
            #pragma unroll
            for (int ocg = 0; ocg < 4; ++ocg)
                #pragma unroll
                for (int r = 0; r < 4; ++r) {
                    const int oc = ocg * 16 + g * 4 + r;
                    out[((size_t)(b * OUTC_ + oc) << 16) + y * 256 + x0 +
                        pxb + ng * 16 + n] = acc[ng][ocg][r] + bv[ocg][r];
                }

        if (doPref) STORE_ROW((y + 2) & 3, pv)
        __syncthreads();
    }
}

extern "C" void kernel_launch(void* const* d_in, const int* in_sizes, int n_in,
                              void* d_out, int out_size, void* d_ws, size_t ws_size,
                              hipStream_t stream) {
    const float* x = (const float*)d_in[0];
    const float* w = (const float*)d_in[1];
    const float* bias = (const float*)d_in[2];
    float* out = (float*)d_out;

    float* act = (float*)d_ws;
    int* sel = (int*)d_ws + 512;
    int* unsel = sel + 128;

    stats_kernel<<<512, 256, 0, stream>>>(x, act);
    select_kernel<<<8, 64, 0, stream>>>(act, sel, unsel);
    copy_kernel<<<24576, 256, 0, stream>>>((const float4*)x, unsel, (float4*)out);
    conv_mfma_kernel<<<512, 256, 0, stream>>>(x, w, bias, sel, out);
}